// Round 11
// baseline (220.563 us; speedup 1.0000x reference)
//
#include <hip/hip_runtime.h>
#include <math.h>

#define NB 8
#define NL 1024
#define ND 512
#define NF 513          // rfft bins of length-1024 transform
#define NT 2047         // L + S - 1
#define TOPK 20         // int(3 * log(1024))

typedef __attribute__((ext_vector_type(8))) short short8;
typedef __attribute__((ext_vector_type(4))) float f32x4;

static __device__ __forceinline__ unsigned short bf16_rne(float x) {
    unsigned int u = __builtin_bit_cast(unsigned int, x);
    unsigned int r = (u + 0x7fffu + ((u >> 16) & 1u)) >> 16;
    return (unsigned short)r;
}
static __device__ __forceinline__ float bf16_to_f(unsigned short h) {
    unsigned int u = ((unsigned int)h) << 16;
    return __builtin_bit_cast(float, u);
}

// ---------------------------------------------------------------------------
// Kernel T: transpose + split-bf16 convert; also zeroes S (replaces memset).
// q[b][l][d] f32 -> Thi/Tlo[(which*NB+b)][d][l] bf16 (hi = rne(x), lo = rne(x-hi))
// ---------------------------------------------------------------------------
__global__ __launch_bounds__(256) void k_tr(const float* __restrict__ q,
                                            const float* __restrict__ kk,
                                            unsigned short* __restrict__ Thi,
                                            unsigned short* __restrict__ Tlo,
                                            float* __restrict__ S) {
    __shared__ float tile[64][65];
    const int which = blockIdx.z;          // 0=q, 1=k
    const int b  = blockIdx.y;
    const int l0 = (blockIdx.x & 15) * 64;
    const int d0 = (blockIdx.x >> 4) * 64;
    const int t = threadIdx.x;
    if (which == 0 && blockIdx.x == 0) {   // 8 blocks zero S[b][*]
        for (int i = t; i < 1023; i += 256) S[b * 1023 + i] = 0.f;
    }
    const float* src = (which ? kk : q) + (size_t)b * NL * ND;
    const int r = t >> 4, c = t & 15;
    #pragma unroll
    for (int rr = 0; rr < 4; ++rr) {
        const float4 v = *(const float4*)&src[(size_t)(l0 + r + 16 * rr) * ND + d0 + c * 4];
        tile[r + 16 * rr][c * 4 + 0] = v.x;
        tile[r + 16 * rr][c * 4 + 1] = v.y;
        tile[r + 16 * rr][c * 4 + 2] = v.z;
        tile[r + 16 * rr][c * 4 + 3] = v.w;
    }
    __syncthreads();
    unsigned short* hi = Thi + ((size_t)which * NB + b) * (size_t)ND * NL;
    unsigned short* lo = Tlo + ((size_t)which * NB + b) * (size_t)ND * NL;
    #pragma unroll
    for (int p = 0; p < 2; ++p) {
        const int c2 = t + 256 * p;        // 0..511
        const int dl = c2 >> 3;            // 0..63
        const int l8 = (c2 & 7) * 8;
        short8 vh, vl;
        #pragma unroll
        for (int i = 0; i < 8; ++i) {
            const float x = tile[l8 + i][dl];
            const unsigned short h = bf16_rne(x);
            vh[i] = (short)h;
            vl[i] = (short)bf16_rne(x - bf16_to_f(h));
        }
        *(short8*)&hi[(size_t)(d0 + dl) * NL + l0 + l8] = vh;
        *(short8*)&lo[(size_t)(d0 + dl) * NL + l0 + l8] = vl;
    }
}

// ---------------------------------------------------------------------------
// Kernel G: barrier-free MFMA Gram GEMM. G = qhi·khi^T + qhi·klo^T + qlo·khi^T.
// r10 post-mortem: the LDS-staged 2-barrier pipeline was lockstep-latency-
// bound at every tiling (36-65 µs for 2.4 µs of MFMA). Here each wave owns an
// independent 64x32 output tile and reads its fragments DIRECTLY from global
// (planes are K-contiguous; per-batch working set 4 MB = one XCD's L2 via the
// b=id&7 affinity). No __syncthreads anywhere; 4096 waves (16/CU, 4/SIMD via
// launch_bounds(256,4) <=128 VGPR) hide latency by TLP. Per-wave diagonal
// epilogue: 5x4 register bins -> private LDS slice (ds_add_f32, same-wave
// ordering via threadfence_block) -> 95 global atomics.
// ---------------------------------------------------------------------------
__global__ __launch_bounds__(256, 4) void k_gemm(const unsigned short* __restrict__ Thi,
                                                 const unsigned short* __restrict__ Tlo,
                                                 float* __restrict__ S) {
    __shared__ float sd[4][96];
    const int id   = blockIdx.x;
    const int b    = id & 7;                   // XCD affinity by batch
    const int rest = id >> 3;                  // 0..127
    const int ntg  = rest & 3;                 // N-tile group (4 nt per block)
    const int mt   = (rest >> 2) & 7;          // 0..7  (64-row M tile)
    const int kq   = rest >> 5;                // 0..3  (split-K quarter)
    const int tid  = threadIdx.x;
    const int w = tid >> 6, lane = tid & 63;
    const int m = lane & 15, g = lane >> 4;    // frag row + k-group
    const int nt = ntg * 4 + w;                // 0..15 (32-col N tile)
    const int D0 = mt * 64, E0 = nt * 32;

    const size_t plane = (size_t)ND * NL;
    const unsigned short* qhi = Thi + (size_t)b * plane;
    const unsigned short* khi = Thi + ((size_t)NB + b) * plane;
    const unsigned short* qlo = Tlo + (size_t)b * plane;
    const unsigned short* klo = Tlo + ((size_t)NB + b) * plane;

    // zero own sd slice (wave-private; no barrier needed)
    sd[w][lane] = 0.f;
    if (lane < 32) sd[w][64 + lane] = 0.f;

    f32x4 acc[4][2];
    #pragma unroll
    for (int i = 0; i < 4; ++i)
        #pragma unroll
        for (int j = 0; j < 2; ++j) acc[i][j] = (f32x4)(0.f);

    const int k00 = kq * 256;
    size_t ar[4], br[2];
    #pragma unroll
    for (int i = 0; i < 4; ++i) ar[i] = (size_t)(D0 + i * 16 + m) * NL;
    #pragma unroll
    for (int j = 0; j < 2; ++j) br[j] = (size_t)(E0 + j * 16 + m) * NL;

    #pragma unroll
    for (int kt = 0; kt < 8; ++kt) {
        const int k0 = k00 + kt * 32 + g * 8;
        short8 ah[4], al[4], bh[2], bl[2];
        #pragma unroll
        for (int i = 0; i < 4; ++i) {
            ah[i] = *(const short8*)&qhi[ar[i] + k0];
            al[i] = *(const short8*)&qlo[ar[i] + k0];
        }
        #pragma unroll
        for (int j = 0; j < 2; ++j) {
            bh[j] = *(const short8*)&khi[br[j] + k0];
            bl[j] = *(const short8*)&klo[br[j] + k0];
        }
        #pragma unroll
        for (int i = 0; i < 4; ++i)
            #pragma unroll
            for (int j = 0; j < 2; ++j) {
                acc[i][j] = __builtin_amdgcn_mfma_f32_16x16x32_bf16(ah[i], bh[j], acc[i][j], 0, 0, 0);
                acc[i][j] = __builtin_amdgcn_mfma_f32_16x16x32_bf16(ah[i], bl[j], acc[i][j], 0, 0, 0);
                acc[i][j] = __builtin_amdgcn_mfma_f32_16x16x32_bf16(al[i], bh[j], acc[i][j], 0, 0, 0);
            }
    }

    // --- per-wave diagonal epilogue ---
    // delta = (D0-E0) + (i-j)*16 + (g*4+r2) - m; local idx = u*16 + g*4-m+r2+15
    float bin[5][4];
    #pragma unroll
    for (int u = 0; u < 5; ++u)
        #pragma unroll
        for (int r2 = 0; r2 < 4; ++r2) bin[u][r2] = 0.f;
    #pragma unroll
    for (int i = 0; i < 4; ++i)
        #pragma unroll
        for (int j = 0; j < 2; ++j)
            #pragma unroll
            for (int r2 = 0; r2 < 4; ++r2) bin[i - j + 1][r2] += acc[i][j][r2];
    const int baseidx = g * 4 - m + 15;        // [0,27]
    #pragma unroll
    for (int u = 0; u < 5; ++u)
        #pragma unroll
        for (int r2 = 0; r2 < 4; ++r2)
            atomicAdd(&sd[w][u * 16 + baseidx + r2], bin[u][r2]);
    __threadfence_block();                     // order LDS atomics vs reads (same wave)
    const int gbase = b * 1023 + 511 + (D0 - E0) - 31;
    #pragma unroll
    for (int t2 = 0; t2 < 2; ++t2) {
        const int idx = lane + 64 * t2;
        if (idx < 95) atomicAdd(&S[gbase + idx], sd[w][idx]);
    }
}

// ---------------------------------------------------------------------------
// Kernel P: P̄[b][f] = sum_j S[b][j] e^{-2πi f (j-511)/1024}.
// One wave per (b,f): lanes split j, exact sincosf per term, butterfly reduce.
// ---------------------------------------------------------------------------
__global__ __launch_bounds__(64) void k_pdft(const float* __restrict__ S,
                                             float* __restrict__ pbar) {
    const int b = blockIdx.y;
    const int f = blockIdx.x;              // 0..512
    const int lane = threadIdx.x;
    const float w = 2.0f * 3.14159265358979323846f / 1024.0f;
    float re = 0.f, im = 0.f;
    #pragma unroll
    for (int i = 0; i < 16; ++i) {
        const int j = lane + 64 * i;
        if (j < 1023) {
            const int mm = (f * (j - 511)) & 1023;   // exact mod (pow2, two's compl.)
            float s, c;
            sincosf(w * (float)mm, &s, &c);
            const float x = S[b * 1023 + j];
            re = fmaf(x, c, re);
            im = fmaf(x, -s, im);
        }
    }
    #pragma unroll
    for (int off = 32; off; off >>= 1) {
        re += __shfl_xor(re, off);
        im += __shfl_xor(im, off);
    }
    if (lane == 0) {
        pbar[b * 2 * NF + 2 * f]     = re;
        pbar[b * 2 * NF + 2 * f + 1] = im;
    }
}

// ---------------------------------------------------------------------------
// Kernel B: mean_value[b,t] = (1/(2047*1024)) * (P̄[0] + 2Σ_{f=1..512}
//            (P̄re[f] cos(2πft/2047) - P̄im[f] sin(2πft/2047)))
// One wave per (b,t), 4 waves/block; lanes split f, butterfly reduce.
// ---------------------------------------------------------------------------
__global__ __launch_bounds__(256) void k_mean(const float* __restrict__ pbar,
                                              float* __restrict__ mv) {
    __shared__ float P[2 * NF];
    const int b = blockIdx.y;
    for (int i = threadIdx.x; i < 2 * NF; i += 256)
        P[i] = pbar[(size_t)b * (2 * NF) + i];
    __syncthreads();
    const int wave = threadIdx.x >> 6, lane = threadIdx.x & 63;
    const int t = blockIdx.x * 4 + wave;   // 0..2047
    if (t >= NT) return;
    const float w2 = 2.0f * 3.14159265358979323846f / 2047.0f;
    float acc = 0.f;
    #pragma unroll
    for (int i = 0; i < 8; ++i) {
        const int f = 1 + lane + 64 * i;   // covers 1..512 exactly
        const int mm = (f * t) % 2047;
        float s, c;
        sincosf(w2 * (float)mm, &s, &c);
        acc = fmaf(P[2 * f], c, acc);
        acc = fmaf(-P[2 * f + 1], s, acc);
    }
    acc *= 2.0f;
    #pragma unroll
    for (int off = 32; off; off >>= 1) acc += __shfl_xor(acc, off);
    if (lane == 0)
        mv[(size_t)b * NT + t] = (acc + P[0]) * (1.0f / (2047.0f * 1024.0f));
}

// ---------------------------------------------------------------------------
// Kernel C: per-batch exact top-20 (ties -> lower index), softmax; batch 0's
// indices -> shifts. 256 threads: 8-iter scans + wave/LDS reduce.
// ---------------------------------------------------------------------------
__global__ __launch_bounds__(256) void k_topk(const float* __restrict__ mv,
                                              float* __restrict__ wts,
                                              int* __restrict__ shifts) {
    __shared__ float v[NT];
    __shared__ float topv[TOPK];
    __shared__ int   topi[TOPK];
    __shared__ float wv[4];
    __shared__ int   wi[4];
    const int b = blockIdx.x;
    const int t = threadIdx.x;
    const int lane = t & 63, wave = t >> 6;
    for (int i = t; i < NT; i += 256) v[i] = mv[(size_t)b * NT + i];
    __syncthreads();
    for (int kkk = 0; kkk < TOPK; ++kkk) {
        float bv = -INFINITY; int bi = 0x7fffffff;
        #pragma unroll
        for (int s = 0; s < 8; ++s) {
            const int i = t + 256 * s;
            if (i < NT) {
                const float x = v[i];
                if (x > bv) { bv = x; bi = i; }
            }
        }
        #pragma unroll
        for (int off = 32; off; off >>= 1) {
            const float ov = __shfl_down(bv, off);
            const int   oi = __shfl_down(bi, off);
            if (ov > bv || (ov == bv && oi < bi)) { bv = ov; bi = oi; }
        }
        if (lane == 0) { wv[wave] = bv; wi[wave] = bi; }
        __syncthreads();
        if (t == 0) {
            bv = wv[0]; bi = wi[0];
            #pragma unroll
            for (int ww = 1; ww < 4; ++ww)
                if (wv[ww] > bv || (wv[ww] == bv && wi[ww] < bi)) { bv = wv[ww]; bi = wi[ww]; }
            topv[kkk] = bv; topi[kkk] = bi;
            v[bi] = -INFINITY;
        }
        __syncthreads();
    }
    if (t == 0) {
        float m = topv[0], sum = 0.f, e[TOPK];
        #pragma unroll
        for (int i = 0; i < TOPK; ++i) { e[i] = expf(topv[i] - m); sum += e[i]; }
        #pragma unroll
        for (int i = 0; i < TOPK; ++i) wts[b * TOPK + i] = e[i] / sum;
        if (b == 0) {
            #pragma unroll
            for (int i = 0; i < TOPK; ++i) shifts[i] = topi[i];
        }
    }
}

// ---------------------------------------------------------------------------
// Kernel D: out[b,l,:] = Σ_k w[b,k] * values[b, (l+shift_k) & 1023, :]
// b = blockIdx.x & 7: XCD affinity so values[b] (2.1 MB) stays L2-resident.
// ---------------------------------------------------------------------------
__global__ __launch_bounds__(128) void k_out(const float* __restrict__ vals,
                                             const float* __restrict__ wts,
                                             const int* __restrict__ shifts,
                                             float* __restrict__ out) {
    __shared__ float w[TOPK];
    __shared__ int   sh[TOPK];
    const int id = blockIdx.x;
    const int b = id & 7;                // XCD affinity
    const int l = id >> 3;
    const int t = threadIdx.x;
    if (t < TOPK) { w[t] = wts[b * TOPK + t]; sh[t] = shifts[t]; }
    __syncthreads();
    float4 acc = make_float4(0.f, 0.f, 0.f, 0.f);
    const float4* vb = (const float4*)(vals + (size_t)b * NL * ND);
    #pragma unroll 4
    for (int kkk = 0; kkk < TOPK; ++kkk) {
        const int sl = (l + sh[kkk]) & (NL - 1);
        const float4 x = vb[(size_t)sl * (ND / 4) + t];
        const float wk = w[kkk];
        acc.x = fmaf(wk, x.x, acc.x);
        acc.y = fmaf(wk, x.y, acc.y);
        acc.z = fmaf(wk, x.z, acc.z);
        acc.w = fmaf(wk, x.w, acc.w);
    }
    ((float4*)out)[((size_t)b * NL + l) * (ND / 4) + t] = acc;
}

extern "C" void kernel_launch(void* const* d_in, const int* in_sizes, int n_in,
                              void* d_out, int out_size, void* d_ws, size_t ws_size,
                              hipStream_t stream) {
    const float* q = (const float*)d_in[0];
    const float* k = (const float*)d_in[1];
    const float* v = (const float*)d_in[2];
    float* out    = (float*)d_out;

    const size_t plane = (size_t)ND * NL;                 // 512*1024
    unsigned short* Thi = (unsigned short*)d_ws;          // 2*NB planes bf16
    unsigned short* Tlo = Thi + 2 * NB * plane;           // 2*NB planes bf16
    float* S      = (float*)(Tlo + 2 * NB * plane);       // NB * 1023
    float* pbar   = S + NB * 1023;                        // NB * 2*NF
    float* mv     = pbar + NB * 2 * NF;                   // NB * NT
    float* wts    = mv + NB * NT;                         // NB * TOPK
    int*   shifts = (int*)(wts + NB * TOPK);              // TOPK ints

    k_tr  <<<dim3(128, NB, 2), 256, 0, stream>>>(q, k, Thi, Tlo, S);
    k_gemm<<<1024, 256, 0, stream>>>(Thi, Tlo, S);
    k_pdft<<<dim3(NF, NB), 64, 0, stream>>>(S, pbar);
    k_mean<<<dim3(512, NB), 256, 0, stream>>>(pbar, mv);
    k_topk<<<NB, 256, 0, stream>>>(mv, wts, shifts);
    k_out <<<NL * NB, 128, 0, stream>>>(v, wts, shifts, out);
}